// Round 1
// baseline (2596.816 us; speedup 1.0000x reference)
//
#include <hip/hip_runtime.h>
#include <math.h>

#define NN 50000
#define NE 800000
#define FD 100
#define HD 128
#define CD 40
#define EPSF 1e-5f

// row_ptr[i] = first edge index with seg_ids >= i (seg_ids sorted ascending)
__global__ void k_rowptr(const int* __restrict__ seg, int* __restrict__ rp) {
  int i = blockIdx.x * blockDim.x + threadIdx.x;
  if (i > NN) return;
  int lo = 0, hi = NE;
  while (lo < hi) { int mid = (lo + hi) >> 1; if (seg[mid] < i) lo = mid + 1; else hi = mid; }
  rp[i] = lo;
}

// Block-per-node (grid-stride). thread j in [0,128) owns W1x row j in VGPRs.
// Pass 1 over node's edges: f accumulation + per-segment rowsum/rowsumsq of nbr1.
// Local sm/inv, then pass 2 recomputes nbr1 rows -> normalize+relu -> f2 mean.
// Also writes hpre = x @ W1x^T (partial for layer-1 node term).
__global__ __launch_bounds__(128) void k_edges(
    const float* __restrict__ x, const float* __restrict__ nbr,
    const int* __restrict__ rp, const float* __restrict__ W1x,
    const float* __restrict__ g1p, const float* __restrict__ b1p,
    float* __restrict__ f, float* __restrict__ f2, float* __restrict__ hpre) {
  const int j = threadIdx.x;
  float w[FD];
#pragma unroll
  for (int k = 0; k < FD; ++k) w[k] = W1x[j * FD + k];
  const float g1 = g1p[0], b1 = b1p[0];
  __shared__ float red[4];
  __shared__ float bcast[2];
  for (int i = blockIdx.x; i < NN; i += gridDim.x) {
    const int s = rp[i], e = rp[i + 1];
    const int cnt = e - s;
    float facc = 0.f, rs = 0.f, rsq = 0.f;
    for (int ed = s; ed < e; ++ed) {
      const float* row = nbr + (size_t)ed * FD;  // uniform address -> s_load
      float acc = 0.f;
#pragma unroll
      for (int k = 0; k < FD; ++k) acc = fmaf(w[k], row[k], acc);
      if (j < FD) facc += row[j];                // per-lane coalesced (L2 hit)
      rs += acc;
      rsq = fmaf(acc, acc, rsq);
    }
    // block-reduce rs, rsq over 128 threads (2 waves)
    float a = rs, b = rsq;
#pragma unroll
    for (int off = 32; off > 0; off >>= 1) { a += __shfl_down(a, off); b += __shfl_down(b, off); }
    if ((j & 63) == 0) { red[(j >> 6) * 2] = a; red[(j >> 6) * 2 + 1] = b; }
    __syncthreads();
    if (j == 0) {
      float RS = red[0] + red[2], RQ = red[1] + red[3];
      float ne = fmaxf((float)cnt * (float)HD, 1.f);
      float smv = RS / ne;
      float var = RQ / ne - smv * smv;
      bcast[0] = smv;
      bcast[1] = rsqrtf(var + EPSF);
    }
    __syncthreads();
    const float sm = bcast[0], inv = bcast[1];
    // pass 2: recompute nbr1 row, normalize+relu, accumulate segment mean f2
    float f2acc = 0.f;
    for (int ed = s; ed < e; ++ed) {
      const float* row = nbr + (size_t)ed * FD;
      float acc = 0.f;
#pragma unroll
      for (int k = 0; k < FD; ++k) acc = fmaf(w[k], row[k], acc);
      float z = fmaf(g1, (acc - sm) * inv, b1);
      f2acc += fmaxf(z, 0.f);
    }
    const float rc = 1.f / (float)(cnt > 0 ? cnt : 1);
    f2[(size_t)i * HD + j] = f2acc * rc;
    if (j < FD) f[(size_t)i * FD + j] = facc * rc;
    // hpre partial: x @ W1x^T (reuses w[])
    float accx = 0.f;
    const float* xr = x + (size_t)i * FD;
#pragma unroll
    for (int k = 0; k < FD; ++k) accx = fmaf(w[k], xr[k], accx);
    hpre[(size_t)i * HD + j] = accx;
  }
}

// hpre += f @ W1n^T ; accumulate BN1 scalar stats (sum, sumsq) via block reduce + atomics
__global__ __launch_bounds__(128) void k_h1(
    const float* __restrict__ f, const float* __restrict__ W1n,
    float* __restrict__ hpre, float* __restrict__ stats) {
  const int j = threadIdx.x;
  float w[FD];
#pragma unroll
  for (int k = 0; k < FD; ++k) w[k] = W1n[j * FD + k];
  float ls = 0.f, lsq = 0.f;
  for (int i = blockIdx.x; i < NN; i += gridDim.x) {
    const float* fr = f + (size_t)i * FD;  // uniform -> s_load
    float acc = hpre[(size_t)i * HD + j];
#pragma unroll
    for (int k = 0; k < FD; ++k) acc = fmaf(w[k], fr[k], acc);
    hpre[(size_t)i * HD + j] = acc;
    ls += acc;
    lsq = fmaf(acc, acc, lsq);
  }
#pragma unroll
  for (int off = 32; off > 0; off >>= 1) { ls += __shfl_down(ls, off); lsq += __shfl_down(lsq, off); }
  __shared__ float sred[4];
  if ((j & 63) == 0) { sred[(j >> 6) * 2] = ls; sred[(j >> 6) * 2 + 1] = lsq; }
  __syncthreads();
  if (j == 0) { atomicAdd(&stats[0], sred[0] + sred[2]); atomicAdd(&stats[1], sred[1] + sred[3]); }
}

// in-place scalar BatchNorm + ReLU over [NN*HD] using accumulated sum/sumsq at stats[so..so+1]
__global__ void k_bn(float* __restrict__ t, const float* __restrict__ stats, int so,
                     const float* __restrict__ gp, const float* __restrict__ bp) {
  const float cntf = (float)NN * (float)HD;
  const float m = stats[so] / cntf;
  const float var = stats[so + 1] / cntf - m * m;
  const float inv = rsqrtf(var + EPSF);
  const float g = gp[0], b = bp[0];
  const size_t tot = (size_t)NN * HD;
  for (size_t idx = (size_t)blockIdx.x * blockDim.x + threadIdx.x; idx < tot;
       idx += (size_t)gridDim.x * blockDim.x) {
    t[idx] = fmaxf(fmaf(g, (t[idx] - m) * inv, b), 0.f);
  }
}

// out[i][j] (+)= sum_k in[i][k] * W[j][k]  (K = HD). Optional BN2 stats accumulation.
template <bool ADD, bool STATS>
__global__ __launch_bounds__(128) void k_gemv_h(
    const float* __restrict__ in, const float* __restrict__ W,
    float* __restrict__ out, float* __restrict__ stats) {
  const int j = threadIdx.x;
  float w[HD];
#pragma unroll
  for (int k = 0; k < HD; ++k) w[k] = W[j * HD + k];
  float ls = 0.f, lsq = 0.f;
  for (int i = blockIdx.x; i < NN; i += gridDim.x) {
    const float* r = in + (size_t)i * HD;  // uniform -> s_load
    float acc = ADD ? out[(size_t)i * HD + j] : 0.f;
#pragma unroll
    for (int k = 0; k < HD; ++k) acc = fmaf(w[k], r[k], acc);
    out[(size_t)i * HD + j] = acc;
    if (STATS) { ls += acc; lsq = fmaf(acc, acc, lsq); }
  }
  if (STATS) {
#pragma unroll
    for (int off = 32; off > 0; off >>= 1) { ls += __shfl_down(ls, off); lsq += __shfl_down(lsq, off); }
    __shared__ float sred[4];
    if ((j & 63) == 0) { sred[(j >> 6) * 2] = ls; sred[(j >> 6) * 2 + 1] = lsq; }
    __syncthreads();
    if (j == 0) { atomicAdd(&stats[2], sred[0] + sred[2]); atomicAdd(&stats[3], sred[1] + sred[3]); }
  }
}

// classifier: out[i][c] = bc[c] + sum_k hb2[i][k] * Wc[c][k]
// thread = (node_sub in [0,3), c in [0,40)); Wc row in VGPRs, float4 loads.
__global__ __launch_bounds__(128) void k_out(
    const float* __restrict__ h, const float* __restrict__ Wc,
    const float* __restrict__ bc, float* __restrict__ out) {
  const int t = threadIdx.x;
  const int nsub = t / CD, c = t - nsub * CD;
  const bool act = (t < 3 * CD);
  float4 w[HD / 4];
  float bias = 0.f;
  if (act) {
    const float4* wr = (const float4*)(Wc + (size_t)c * HD);
#pragma unroll
    for (int k = 0; k < HD / 4; ++k) w[k] = wr[k];
    bias = bc[c];
  }
  for (int i0 = blockIdx.x * 3; i0 < NN; i0 += gridDim.x * 3) {
    const int i = i0 + nsub;
    if (act && i < NN) {
      const float4* r = (const float4*)(h + (size_t)i * HD);
      float acc = bias;
#pragma unroll
      for (int k = 0; k < HD / 4; ++k) {
        float4 v = r[k];
        acc = fmaf(w[k].x, v.x, acc);
        acc = fmaf(w[k].y, v.y, acc);
        acc = fmaf(w[k].z, v.z, acc);
        acc = fmaf(w[k].w, v.w, acc);
      }
      out[(size_t)i * CD + c] = acc;
    }
  }
}

extern "C" void kernel_launch(void* const* d_in, const int* in_sizes, int n_in,
                              void* d_out, int out_size, void* d_ws, size_t ws_size,
                              hipStream_t stream) {
  const float* x   = (const float*)d_in[0];
  const float* nbr = (const float*)d_in[1];
  const int*   seg = (const int*)d_in[2];
  const float* W1x = (const float*)d_in[3];
  const float* W1n = (const float*)d_in[4];
  const float* g1  = (const float*)d_in[5];
  const float* b1  = (const float*)d_in[6];
  const float* W2x = (const float*)d_in[7];
  const float* W2n = (const float*)d_in[8];
  const float* g2  = (const float*)d_in[9];
  const float* b2  = (const float*)d_in[10];
  const float* Wc  = (const float*)d_in[11];
  const float* bc  = (const float*)d_in[12];
  float* out = (float*)d_out;

  char* p = (char*)d_ws;
  auto alloc = [&](size_t bytes) {
    char* q = p;
    p += (bytes + 255) & ~(size_t)255;
    return q;
  };
  int*   rp    = (int*)  alloc(sizeof(int) * (NN + 1));
  float* f     = (float*)alloc(sizeof(float) * (size_t)NN * FD);
  float* f2    = (float*)alloc(sizeof(float) * (size_t)NN * HD);
  float* hpre  = (float*)alloc(sizeof(float) * (size_t)NN * HD);
  float* h2    = (float*)alloc(sizeof(float) * (size_t)NN * HD);
  float* stats = (float*)alloc(sizeof(float) * 4);

  hipMemsetAsync(stats, 0, sizeof(float) * 4, stream);
  k_rowptr<<<(NN + 256) / 256, 256, 0, stream>>>(seg, rp);
  k_edges<<<2048, 128, 0, stream>>>(x, nbr, rp, W1x, g1, b1, f, f2, hpre);
  k_h1<<<1024, 128, 0, stream>>>(f, W1n, hpre, stats);
  k_bn<<<2048, 256, 0, stream>>>(hpre, stats, 0, g1, b1);                 // hb1 in place
  k_gemv_h<false, false><<<1024, 128, 0, stream>>>(hpre, W2x, h2, stats); // h2 = hb1@W2x^T
  k_gemv_h<true, true><<<1024, 128, 0, stream>>>(f2, W2n, h2, stats);     // h2 += f2@W2n^T + BN2 stats
  k_bn<<<2048, 256, 0, stream>>>(h2, stats, 2, g2, b2);                   // hb2 in place
  k_out<<<2048, 128, 0, stream>>>(h2, Wc, bc, out);
}

// Round 2
// 845.762 us; speedup vs baseline: 3.0704x; 3.0704x over previous
//
#include <hip/hip_runtime.h>
#include <math.h>

#define NN 50000
#define NE 800000
#define FD 100
#define HD 128
#define CD 40
#define EPSF 1e-5f
#define MTOT (NE + NN)

typedef __attribute__((ext_vector_type(8))) short short8;
typedef __attribute__((ext_vector_type(4))) float f32x4;

__device__ __forceinline__ unsigned short f2bf(float x) {
  unsigned u = __float_as_uint(x);
  unsigned r = (u + 0x7FFFu + ((u >> 16) & 1u)) >> 16;  // RNE
  return (unsigned short)r;
}
__device__ __forceinline__ float bf2f(unsigned short b) {
  return __uint_as_float(((unsigned)b) << 16);
}

// row_ptr[i] = first edge index with seg_ids >= i (seg_ids sorted ascending)
__global__ void k_rowptr(const int* __restrict__ seg, int* __restrict__ rp) {
  int i = blockIdx.x * blockDim.x + threadIdx.x;
  if (i > NN) return;
  int lo = 0, hi = NE;
  while (lo < hi) { int mid = (lo + hi) >> 1; if (seg[mid] < i) lo = mid + 1; else hi = mid; }
  rp[i] = lo;
}

// ---------------- fast path: MFMA edge GEMM ----------------
// M = NE edges (A=nbr) stacked with NN nodes (A=x); B[k][n] = W1x[n][k].
// Per block: 128 rows x 128 cols, K=128 (100 + zero pad). 8 waves, each wave
// owns 16 rows x all 128 cols. LDS XOR-swizzled (T2). Outputs:
//   edge rows -> nbr1 bf16 + per-edge rowsum/rowsumsq (f32, exact accumulators)
//   node rows -> hpre f32 (= x @ W1x^T)
__global__ __launch_bounds__(512) void k_gemm1(
    const float* __restrict__ nbr, const float* __restrict__ x,
    const float* __restrict__ W1x,
    unsigned short* __restrict__ nbr1, float* __restrict__ hpre,
    float* __restrict__ es, float* __restrict__ eq) {
  __shared__ char Ab[32768];  // [128 rows][128 k] bf16, swizzled
  __shared__ char Bb[32768];  // [128 n  ][128 k] bf16, swizzled
  const int tid = threadIdx.x;
  const long rowbase = (long)blockIdx.x * 128;

  // ---- stage A (f32 -> bf16) ----
  {
    const int r = tid >> 2, q = tid & 3;
    const long rg = rowbase + r;
    const float* src = (rg < NE) ? (nbr + rg * FD)
                                 : (rg < MTOT ? x + (rg - NE) * FD : nullptr);
    const int c0 = q * 32;
    float v[32];
#pragma unroll
    for (int i4 = 0; i4 < 8; ++i4) {
      const int c = c0 + i4 * 4;
      float4 t = make_float4(0.f, 0.f, 0.f, 0.f);
      if (src && c < FD) t = *(const float4*)(src + c);  // FD=100 -> c+3<=99 always valid when c<100
      v[i4 * 4 + 0] = t.x; v[i4 * 4 + 1] = t.y; v[i4 * 4 + 2] = t.z; v[i4 * 4 + 3] = t.w;
    }
    char* ab = Ab + r * 256;
#pragma unroll
    for (int h = 0; h < 4; ++h) {
      short8 s;
#pragma unroll
      for (int e = 0; e < 8; ++e) s[e] = (short)f2bf(v[h * 8 + e]);
      const int colb = (c0 * 2 + h * 16) ^ ((r & 7) << 4);
      *(short8*)(ab + colb) = s;
    }
  }
  // ---- stage B (W1x rows, f32 -> bf16) ----
  {
    const int r = tid >> 2, q = tid & 3;
    const float* src = W1x + (size_t)r * FD;
    const int c0 = q * 32;
    float v[32];
#pragma unroll
    for (int i4 = 0; i4 < 8; ++i4) {
      const int c = c0 + i4 * 4;
      float4 t = make_float4(0.f, 0.f, 0.f, 0.f);
      if (c < FD) t = *(const float4*)(src + c);
      v[i4 * 4 + 0] = t.x; v[i4 * 4 + 1] = t.y; v[i4 * 4 + 2] = t.z; v[i4 * 4 + 3] = t.w;
    }
    char* bb = Bb + r * 256;
#pragma unroll
    for (int h = 0; h < 4; ++h) {
      short8 s;
#pragma unroll
      for (int e = 0; e < 8; ++e) s[e] = (short)f2bf(v[h * 8 + e]);
      const int colb = (c0 * 2 + h * 16) ^ ((r & 7) << 4);
      *(short8*)(bb + colb) = s;
    }
  }
  __syncthreads();

  // ---- compute ----
  const int w = tid >> 6;          // wave 0..7 -> rows w*16..w*16+15
  const int l = tid & 63;
  const int lr = l & 15, lh = l >> 4;

  short8 af[4];
#pragma unroll
  for (int kk = 0; kk < 4; ++kk) {
    const int row = w * 16 + lr;
    const int colb = (lh * 16 + kk * 64) ^ ((row & 7) << 4);
    af[kk] = *(short8*)(Ab + row * 256 + colb);
  }

  float rs[4] = {0.f, 0.f, 0.f, 0.f}, rq[4] = {0.f, 0.f, 0.f, 0.f};
#pragma unroll
  for (int nt = 0; nt < 8; ++nt) {
    f32x4 acc = {0.f, 0.f, 0.f, 0.f};
#pragma unroll
    for (int kk = 0; kk < 4; ++kk) {
      const int n = nt * 16 + lr;
      const int colb = (lh * 16 + kk * 64) ^ ((n & 7) << 4);
      short8 bfrag = *(short8*)(Bb + n * 256 + colb);
      acc = __builtin_amdgcn_mfma_f32_16x16x32_bf16(af[kk], bfrag, acc, 0, 0, 0);
    }
    const int col = nt * 16 + lr;  // C: col = lane&15, row = (lane>>4)*4 + reg
#pragma unroll
    for (int r = 0; r < 4; ++r) {
      const long rg = rowbase + w * 16 + lh * 4 + r;
      const float val = acc[r];
      if (rg < NE) {
        nbr1[rg * HD + col] = f2bf(val);
        rs[r] += val;
        rq[r] = fmaf(val, val, rq[r]);
      } else if (rg < MTOT) {
        hpre[(rg - NE) * HD + col] = val;
      }
    }
  }
  // per-edge rowsum/rowsumsq: reduce over lr (low 4 lane bits)
#pragma unroll
  for (int r = 0; r < 4; ++r) {
    float s = rs[r], sq = rq[r];
#pragma unroll
    for (int off = 1; off < 16; off <<= 1) { s += __shfl_xor(s, off); sq += __shfl_xor(sq, off); }
    if (lr == 0) {
      const long rg = rowbase + w * 16 + lh * 4 + r;
      if (rg < NE) { es[rg] = s; eq[rg] = sq; }
    }
  }
}

// f[i][j] = mean over segment of nbr[ed][j]  (block per node, j<FD)
__global__ __launch_bounds__(128) void k_f(
    const float* __restrict__ nbr, const int* __restrict__ rp, float* __restrict__ f) {
  const int i = blockIdx.x;
  const int j = threadIdx.x;
  const int s = rp[i], e = rp[i + 1];
  if (j >= FD) return;
  float acc = 0.f;
  for (int ed = s; ed < e; ++ed) acc += nbr[(size_t)ed * FD + j];
  const int cnt = e - s;
  f[(size_t)i * FD + j] = acc / (float)(cnt > 0 ? cnt : 1);
}

// per-node BN stats from per-edge sums: sm, inv, rc
__global__ void k_nodestats(const int* __restrict__ rp, const float* __restrict__ es,
                            const float* __restrict__ eq, float2* __restrict__ smi,
                            float* __restrict__ rcv) {
  const int i = blockIdx.x * blockDim.x + threadIdx.x;
  if (i >= NN) return;
  const int s = rp[i], e = rp[i + 1];
  float S = 0.f, Q = 0.f;
  for (int ed = s; ed < e; ++ed) { S += es[ed]; Q += eq[ed]; }
  const int cnt = e - s;
  const float ne = fmaxf((float)cnt * (float)HD, 1.f);
  const float sm = S / ne;
  const float var = Q / ne - sm * sm;
  smi[i] = make_float2(sm, rsqrtf(var + EPSF));
  rcv[i] = 1.f / (float)(cnt > 0 ? cnt : 1);
}

// f2[i][j] = mean over segment of relu(g1*(nbr1-sm)*inv + b1)
__global__ __launch_bounds__(128) void k_f2(
    const unsigned short* __restrict__ nbr1, const int* __restrict__ rp,
    const float2* __restrict__ smi, const float* __restrict__ rcv,
    const float* __restrict__ g1p, const float* __restrict__ b1p,
    float* __restrict__ f2) {
  const int i = blockIdx.x;
  const int j = threadIdx.x;
  const int s = rp[i], e = rp[i + 1];
  const float2 mi = smi[i];
  const float g = g1p[0], b = b1p[0];
  float acc = 0.f;
  for (int ed = s; ed < e; ++ed) {
    const float v = bf2f(nbr1[(size_t)ed * HD + j]);
    acc += fmaxf(fmaf(g, (v - mi.x) * mi.y, b), 0.f);
  }
  f2[(size_t)i * HD + j] = acc * rcv[i];
}

// ---------------- shared node-level kernels ----------------

// hpre += f @ W1n^T ; accumulate BN1 scalar stats
__global__ __launch_bounds__(128) void k_h1(
    const float* __restrict__ f, const float* __restrict__ W1n,
    float* __restrict__ hpre, float* __restrict__ stats) {
  const int j = threadIdx.x;
  float w[FD];
#pragma unroll
  for (int k = 0; k < FD; ++k) w[k] = W1n[j * FD + k];
  float ls = 0.f, lsq = 0.f;
  for (int i = blockIdx.x; i < NN; i += gridDim.x) {
    const float* fr = f + (size_t)i * FD;
    float acc = hpre[(size_t)i * HD + j];
#pragma unroll
    for (int k = 0; k < FD; ++k) acc = fmaf(w[k], fr[k], acc);
    hpre[(size_t)i * HD + j] = acc;
    ls += acc;
    lsq = fmaf(acc, acc, lsq);
  }
#pragma unroll
  for (int off = 32; off > 0; off >>= 1) { ls += __shfl_down(ls, off); lsq += __shfl_down(lsq, off); }
  __shared__ float sred[4];
  if ((j & 63) == 0) { sred[(j >> 6) * 2] = ls; sred[(j >> 6) * 2 + 1] = lsq; }
  __syncthreads();
  if (j == 0) { atomicAdd(&stats[0], sred[0] + sred[2]); atomicAdd(&stats[1], sred[1] + sred[3]); }
}

__global__ void k_bn(float* __restrict__ t, const float* __restrict__ stats, int so,
                     const float* __restrict__ gp, const float* __restrict__ bp) {
  const float cntf = (float)NN * (float)HD;
  const float m = stats[so] / cntf;
  const float var = stats[so + 1] / cntf - m * m;
  const float inv = rsqrtf(var + EPSF);
  const float g = gp[0], b = bp[0];
  const size_t tot = (size_t)NN * HD;
  for (size_t idx = (size_t)blockIdx.x * blockDim.x + threadIdx.x; idx < tot;
       idx += (size_t)gridDim.x * blockDim.x) {
    t[idx] = fmaxf(fmaf(g, (t[idx] - m) * inv, b), 0.f);
  }
}

template <bool ADD, bool STATS>
__global__ __launch_bounds__(128) void k_gemv_h(
    const float* __restrict__ in, const float* __restrict__ W,
    float* __restrict__ out, float* __restrict__ stats) {
  const int j = threadIdx.x;
  float w[HD];
#pragma unroll
  for (int k = 0; k < HD; ++k) w[k] = W[j * HD + k];
  float ls = 0.f, lsq = 0.f;
  for (int i = blockIdx.x; i < NN; i += gridDim.x) {
    const float* r = in + (size_t)i * HD;
    float acc = ADD ? out[(size_t)i * HD + j] : 0.f;
#pragma unroll
    for (int k = 0; k < HD; ++k) acc = fmaf(w[k], r[k], acc);
    out[(size_t)i * HD + j] = acc;
    if (STATS) { ls += acc; lsq = fmaf(acc, acc, lsq); }
  }
  if (STATS) {
#pragma unroll
    for (int off = 32; off > 0; off >>= 1) { ls += __shfl_down(ls, off); lsq += __shfl_down(lsq, off); }
    __shared__ float sred[4];
    if ((j & 63) == 0) { sred[(j >> 6) * 2] = ls; sred[(j >> 6) * 2 + 1] = lsq; }
    __syncthreads();
    if (j == 0) { atomicAdd(&stats[2], sred[0] + sred[2]); atomicAdd(&stats[3], sred[1] + sred[3]); }
  }
}

__global__ __launch_bounds__(128) void k_out(
    const float* __restrict__ h, const float* __restrict__ Wc,
    const float* __restrict__ bc, float* __restrict__ out) {
  const int t = threadIdx.x;
  const int nsub = t / CD, c = t - nsub * CD;
  const bool act = (t < 3 * CD);
  float4 w[HD / 4];
  float bias = 0.f;
  if (act) {
    const float4* wr = (const float4*)(Wc + (size_t)c * HD);
#pragma unroll
    for (int k = 0; k < HD / 4; ++k) w[k] = wr[k];
    bias = bc[c];
  }
  for (int i0 = blockIdx.x * 3; i0 < NN; i0 += gridDim.x * 3) {
    const int i = i0 + nsub;
    if (act && i < NN) {
      const float4* r = (const float4*)(h + (size_t)i * HD);
      float acc = bias;
#pragma unroll
      for (int k = 0; k < HD / 4; ++k) {
        float4 v = r[k];
        acc = fmaf(w[k].x, v.x, acc);
        acc = fmaf(w[k].y, v.y, acc);
        acc = fmaf(w[k].z, v.z, acc);
        acc = fmaf(w[k].w, v.w, acc);
      }
      out[(size_t)i * CD + c] = acc;
    }
  }
}

// ---------------- fallback (round-1 proven) edge kernel ----------------
__global__ __launch_bounds__(128) void k_edges(
    const float* __restrict__ x, const float* __restrict__ nbr,
    const int* __restrict__ rp, const float* __restrict__ W1x,
    const float* __restrict__ g1p, const float* __restrict__ b1p,
    float* __restrict__ f, float* __restrict__ f2, float* __restrict__ hpre) {
  const int j = threadIdx.x;
  float w[FD];
#pragma unroll
  for (int k = 0; k < FD; ++k) w[k] = W1x[j * FD + k];
  const float g1 = g1p[0], b1 = b1p[0];
  __shared__ float red[4];
  __shared__ float bcast[2];
  for (int i = blockIdx.x; i < NN; i += gridDim.x) {
    const int s = rp[i], e = rp[i + 1];
    const int cnt = e - s;
    float facc = 0.f, rssum = 0.f, rsq = 0.f;
    for (int ed = s; ed < e; ++ed) {
      const float* row = nbr + (size_t)ed * FD;
      float acc = 0.f;
#pragma unroll
      for (int k = 0; k < FD; ++k) acc = fmaf(w[k], row[k], acc);
      if (j < FD) facc += row[j];
      rssum += acc;
      rsq = fmaf(acc, acc, rsq);
    }
    float a = rssum, b = rsq;
#pragma unroll
    for (int off = 32; off > 0; off >>= 1) { a += __shfl_down(a, off); b += __shfl_down(b, off); }
    if ((j & 63) == 0) { red[(j >> 6) * 2] = a; red[(j >> 6) * 2 + 1] = b; }
    __syncthreads();
    if (j == 0) {
      float RS = red[0] + red[2], RQ = red[1] + red[3];
      float ne = fmaxf((float)cnt * (float)HD, 1.f);
      float smv = RS / ne;
      float var = RQ / ne - smv * smv;
      bcast[0] = smv;
      bcast[1] = rsqrtf(var + EPSF);
    }
    __syncthreads();
    const float sm = bcast[0], inv = bcast[1];
    float f2acc = 0.f;
    for (int ed = s; ed < e; ++ed) {
      const float* row = nbr + (size_t)ed * FD;
      float acc = 0.f;
#pragma unroll
      for (int k = 0; k < FD; ++k) acc = fmaf(w[k], row[k], acc);
      float z = fmaf(g1, (acc - sm) * inv, b1);
      f2acc += fmaxf(z, 0.f);
    }
    const float rc = 1.f / (float)(cnt > 0 ? cnt : 1);
    f2[(size_t)i * HD + j] = f2acc * rc;
    if (j < FD) f[(size_t)i * FD + j] = facc * rc;
    float accx = 0.f;
    const float* xr = x + (size_t)i * FD;
#pragma unroll
    for (int k = 0; k < FD; ++k) accx = fmaf(w[k], xr[k], accx);
    hpre[(size_t)i * HD + j] = accx;
  }
}

extern "C" void kernel_launch(void* const* d_in, const int* in_sizes, int n_in,
                              void* d_out, int out_size, void* d_ws, size_t ws_size,
                              hipStream_t stream) {
  const float* x   = (const float*)d_in[0];
  const float* nbr = (const float*)d_in[1];
  const int*   seg = (const int*)d_in[2];
  const float* W1x = (const float*)d_in[3];
  const float* W1n = (const float*)d_in[4];
  const float* g1  = (const float*)d_in[5];
  const float* b1  = (const float*)d_in[6];
  const float* W2x = (const float*)d_in[7];
  const float* W2n = (const float*)d_in[8];
  const float* g2  = (const float*)d_in[9];
  const float* b2  = (const float*)d_in[10];
  const float* Wc  = (const float*)d_in[11];
  const float* bc  = (const float*)d_in[12];
  float* out = (float*)d_out;

  char* p = (char*)d_ws;
  auto alloc = [&](size_t bytes) {
    char* q = p;
    p += (bytes + 255) & ~(size_t)255;
    return q;
  };
  // common
  int*   rp    = (int*)  alloc(sizeof(int) * (NN + 1));
  float* f     = (float*)alloc(sizeof(float) * (size_t)NN * FD);
  float* f2    = (float*)alloc(sizeof(float) * (size_t)NN * HD);
  float* hpre  = (float*)alloc(sizeof(float) * (size_t)NN * HD);
  float* h2    = (float*)alloc(sizeof(float) * (size_t)NN * HD);
  float* stats = (float*)alloc(sizeof(float) * 4);
  // fast-path extras
  unsigned short* nbr1 = (unsigned short*)alloc(sizeof(unsigned short) * (size_t)NE * HD);
  float* es   = (float*)alloc(sizeof(float) * (size_t)NE);
  float* eq   = (float*)alloc(sizeof(float) * (size_t)NE);
  float2* smi = (float2*)alloc(sizeof(float2) * (size_t)NN);
  float* rcv  = (float*)alloc(sizeof(float) * (size_t)NN);
  const bool fast = ((size_t)(p - (char*)d_ws) <= ws_size);

  hipMemsetAsync(stats, 0, sizeof(float) * 4, stream);
  k_rowptr<<<(NN + 256) / 256, 256, 0, stream>>>(seg, rp);

  if (fast) {
    k_gemm1<<<(MTOT + 127) / 128, 512, 0, stream>>>(nbr, x, W1x, nbr1, hpre, es, eq);
    k_f<<<NN, 128, 0, stream>>>(nbr, rp, f);
    k_nodestats<<<(NN + 255) / 256, 256, 0, stream>>>(rp, es, eq, smi, rcv);
    k_f2<<<NN, 128, 0, stream>>>(nbr1, rp, smi, rcv, g1, b1, f2);
  } else {
    k_edges<<<2048, 128, 0, stream>>>(x, nbr, rp, W1x, g1, b1, f, f2, hpre);
  }
  k_h1<<<4096, 128, 0, stream>>>(f, W1n, hpre, stats);
  k_bn<<<2048, 256, 0, stream>>>(hpre, stats, 0, g1, b1);
  k_gemv_h<false, false><<<4096, 128, 0, stream>>>(hpre, W2x, h2, stats);
  k_gemv_h<true, true><<<4096, 128, 0, stream>>>(f2, W2n, h2, stats);
  k_bn<<<2048, 256, 0, stream>>>(h2, stats, 2, g2, b2);
  k_out<<<2048, 128, 0, stream>>>(h2, Wc, bc, out);
}

// Round 3
// 645.982 us; speedup vs baseline: 4.0199x; 1.3093x over previous
//
#include <hip/hip_runtime.h>
#include <hip/hip_bf16.h>
#include <math.h>

#define NN 50000
#define NE 800000
#define FD 100
#define HD 128
#define CD 40
#define EPSF 1e-5f
#define NTILE 6250   // NE / 128 exactly
#define TPB_G1 5
#define GRID_G1 1250 // NTILE / TPB_G1

typedef __attribute__((ext_vector_type(8))) short short8;
typedef __attribute__((ext_vector_type(4))) float f32x4;

__device__ __forceinline__ unsigned short f2bf(float x) {
  union { __hip_bfloat16 h; unsigned short u; } cv;
  cv.h = __float2bfloat16(x);
  return cv.u;
}
__device__ __forceinline__ float bf2f(unsigned short b) {
  return __uint_as_float(((unsigned)b) << 16);
}

// row_ptr[i] = first edge index with seg_ids >= i
__global__ void k_rowptr(const int* __restrict__ seg, int* __restrict__ rp) {
  int i = blockIdx.x * blockDim.x + threadIdx.x;
  if (i > NN) return;
  int lo = 0, hi = NE;
  while (lo < hi) { int mid = (lo + hi) >> 1; if (seg[mid] < i) lo = mid + 1; else hi = mid; }
  rp[i] = lo;
}

// convert 32 f32 (in 8 float4) -> 4 swizzled short8 LDS writes (row stride 256B)
__device__ __forceinline__ void cvt_write256(const float4* gv, char* rowbase, int q, int sr) {
  const float* vf = (const float*)gv;
#pragma unroll
  for (int h = 0; h < 4; ++h) {
    short8 s;
#pragma unroll
    for (int e = 0; e < 8; ++e) s[e] = (short)f2bf(vf[h * 8 + e]);
    *(short8*)(rowbase + ((q * 64 + h * 16) ^ ((sr & 7) << 4))) = s;
  }
}

// ---------------- edge GEMM: nbr1 = bf16(nbr @ W1x^T), es/eq row stats ----------------
__global__ __launch_bounds__(512, 2) void k_gemm1(
    const float* __restrict__ nbr, const float* __restrict__ W1x,
    unsigned short* __restrict__ nbr1,
    float* __restrict__ es, float* __restrict__ eq) {
  __shared__ char lds[65536];  // two 32KB A buffers; buf0 doubles as B staging at start
  const int tid = threadIdx.x;
  const int sr = tid >> 2, q = tid & 3;
  const int w = tid >> 6, l = tid & 63, lr = l & 15, lh = l >> 4;

  // stage B = W1x (128 x 100 f32) -> bf16 swizzled into buf0
  {
    float4 gv[8];
    const float* src = W1x + (size_t)sr * FD;
#pragma unroll
    for (int i4 = 0; i4 < 8; ++i4) {
      const int c = q * 32 + i4 * 4;
      gv[i4] = (c < FD) ? *(const float4*)(src + c) : make_float4(0.f, 0.f, 0.f, 0.f);
    }
    cvt_write256(gv, lds + sr * 256, q, sr);
  }
  __syncthreads();
  // B fragments -> registers (reused for all tiles)
  short8 bfr[8][4];
#pragma unroll
  for (int nt = 0; nt < 8; ++nt) {
#pragma unroll
    for (int kk = 0; kk < 4; ++kk) {
      const int n = nt * 16 + lr;
      bfr[nt][kk] = *(short8*)(lds + n * 256 + ((lh * 16 + kk * 64) ^ ((n & 7) << 4)));
    }
  }
  __syncthreads();

  const int t0 = blockIdx.x * TPB_G1;
  float4 gv[8];
  // prologue: stage tile t0 into buf0
  {
    const float* src = nbr + (size_t)(t0 * 128 + sr) * FD;
#pragma unroll
    for (int i4 = 0; i4 < 8; ++i4) {
      const int c = q * 32 + i4 * 4;
      gv[i4] = (c < FD) ? *(const float4*)(src + c) : make_float4(0.f, 0.f, 0.f, 0.f);
    }
    cvt_write256(gv, lds + sr * 256, q, sr);
  }
  int cur = 0;
  for (int s = 0; s < TPB_G1; ++s) {
    // issue next tile's global loads early (latency hides under MFMA)
    if (s + 1 < TPB_G1) {
      const float* src = nbr + (size_t)((t0 + s + 1) * 128 + sr) * FD;
#pragma unroll
      for (int i4 = 0; i4 < 8; ++i4) {
        const int c = q * 32 + i4 * 4;
        gv[i4] = (c < FD) ? *(const float4*)(src + c) : make_float4(0.f, 0.f, 0.f, 0.f);
      }
    }
    __syncthreads();  // buf[cur] ready
    char* bufc = lds + cur * 32768;
    short8 af[4];
    const int arow = w * 16 + lr;
#pragma unroll
    for (int kk = 0; kk < 4; ++kk)
      af[kk] = *(short8*)(bufc + arow * 256 + ((lh * 16 + kk * 64) ^ ((arow & 7) << 4)));

    const size_t rowb = (size_t)(t0 + s) * 128;
    float rs[4] = {0.f, 0.f, 0.f, 0.f}, rq[4] = {0.f, 0.f, 0.f, 0.f};
#pragma unroll
    for (int nt = 0; nt < 8; ++nt) {
      f32x4 acc = {0.f, 0.f, 0.f, 0.f};
#pragma unroll
      for (int kk = 0; kk < 4; ++kk)
        acc = __builtin_amdgcn_mfma_f32_16x16x32_bf16(af[kk], bfr[nt][kk], acc, 0, 0, 0);
      const int col = nt * 16 + lr;
#pragma unroll
      for (int r = 0; r < 4; ++r) {
        const float val = acc[r];
        nbr1[(rowb + w * 16 + lh * 4 + r) * HD + col] = f2bf(val);
        rs[r] += val;
        rq[r] = fmaf(val, val, rq[r]);
      }
    }
#pragma unroll
    for (int r = 0; r < 4; ++r) {
      float a = rs[r], b = rq[r];
#pragma unroll
      for (int off = 1; off < 16; off <<= 1) { a += __shfl_xor(a, off); b += __shfl_xor(b, off); }
      if (lr == 0) {
        const size_t rg = rowb + w * 16 + lh * 4 + r;
        es[rg] = a; eq[rg] = b;
      }
    }
    if (s + 1 < TPB_G1) cvt_write256(gv, lds + (cur ^ 1) * 32768 + sr * 256, q, sr);
    cur ^= 1;
  }
}

// ---------------- segment sums, coalesced chunk + boundary atomics ----------------
__global__ __launch_bounds__(256) void k_f(
    const float* __restrict__ nbr, const int* __restrict__ seg, float* __restrict__ fsum) {
  __shared__ float L[128][104];
  __shared__ int segL[128];
  const int tid = threadIdx.x;
  const size_t base = (size_t)blockIdx.x * 128;
  for (int idx = tid; idx < 3200; idx += 256) {
    const int row = idx / 25, c4 = idx - row * 25;
    float4 v = *(const float4*)(nbr + (base + row) * FD + c4 * 4);
    *(float4*)&L[row][c4 * 4] = v;
  }
  if (tid < 128) segL[tid] = seg[base + tid];
  __syncthreads();
  if (tid < FD) {
    const int nd0 = segL[0], ndL = segL[127];
    int curn = nd0; float acc = 0.f;
    for (int row = 0; row < 128; ++row) {
      const int nd = segL[row];
      if (nd != curn) {
        if (curn == nd0 || curn == ndL) atomicAdd(&fsum[(size_t)curn * FD + tid], acc);
        else fsum[(size_t)curn * FD + tid] = acc;
        acc = 0.f; curn = nd;
      }
      acc += L[row][tid];
    }
    atomicAdd(&fsum[(size_t)curn * FD + tid], acc);
  }
}

__global__ void k_nodestats(const int* __restrict__ rp, const float* __restrict__ es,
                            const float* __restrict__ eq, float2* __restrict__ smi,
                            float* __restrict__ rcv) {
  const int i = blockIdx.x * blockDim.x + threadIdx.x;
  if (i >= NN) return;
  const int s = rp[i], e = rp[i + 1];
  float S = 0.f, Q = 0.f;
  for (int ed = s; ed < e; ++ed) { S += es[ed]; Q += eq[ed]; }
  const int cnt = e - s;
  const float ne = fmaxf((float)cnt * (float)HD, 1.f);
  const float sm = S / ne;
  const float var = Q / ne - sm * sm;
  smi[i] = make_float2(sm, rsqrtf(var + EPSF));
  rcv[i] = 1.f / (float)(cnt > 0 ? cnt : 1);
}

__global__ __launch_bounds__(256) void k_f2(
    const unsigned short* __restrict__ nbr1, const int* __restrict__ seg,
    const float2* __restrict__ smi, const float* __restrict__ g1p,
    const float* __restrict__ b1p, float* __restrict__ f2sum) {
  __shared__ float L[128][132];
  __shared__ int segL[128];
  __shared__ float2 smrow[128];
  const int tid = threadIdx.x;
  const size_t base = (size_t)blockIdx.x * 128;
  for (int idx = tid; idx < 2048; idx += 256) {
    const int row = idx >> 4, c8 = idx & 15;
    short8 v = *(const short8*)(nbr1 + (base + row) * HD + c8 * 8);
    float4 a, b;
    a.x = bf2f((unsigned short)v[0]); a.y = bf2f((unsigned short)v[1]);
    a.z = bf2f((unsigned short)v[2]); a.w = bf2f((unsigned short)v[3]);
    b.x = bf2f((unsigned short)v[4]); b.y = bf2f((unsigned short)v[5]);
    b.z = bf2f((unsigned short)v[6]); b.w = bf2f((unsigned short)v[7]);
    *(float4*)&L[row][c8 * 8] = a;
    *(float4*)&L[row][c8 * 8 + 4] = b;
  }
  if (tid < 128) {
    const int nd = seg[base + tid];
    segL[tid] = nd;
    smrow[tid] = smi[nd];
  }
  __syncthreads();
  const float g = g1p[0], bb = b1p[0];
  if (tid < HD) {
    const int nd0 = segL[0], ndL = segL[127];
    int curn = nd0; float acc = 0.f;
    for (int row = 0; row < 128; ++row) {
      const int nd = segL[row];
      if (nd != curn) {
        if (curn == nd0 || curn == ndL) atomicAdd(&f2sum[(size_t)curn * HD + tid], acc);
        else f2sum[(size_t)curn * HD + tid] = acc;
        acc = 0.f; curn = nd;
      }
      const float2 mi = smrow[row];
      acc += fmaxf(fmaf(g, (L[row][tid] - mi.x) * mi.y, bb), 0.f);
    }
    atomicAdd(&f2sum[(size_t)curn * HD + tid], acc);
  }
}

// ---------------- node GEMMs (MFMA, K=256 two-half) ----------------
// L2=false: out = x@W1x^T + (fsum*rcv)@W1n^T, stats -> so[0..1]
// L2=true : out = bnrelu(hpre)@W2x^T + (f2sum*rcv)@W2n^T, stats -> so[0..1]
template <bool L2>
__global__ __launch_bounds__(512) void k_ngemm(
    const float* __restrict__ P1, const float* __restrict__ P2,
    const float* __restrict__ rcv,
    const float* __restrict__ WA, const float* __restrict__ WB,
    const float* __restrict__ stats_in,
    const float* __restrict__ gp, const float* __restrict__ bp,
    float* __restrict__ out, float* __restrict__ so) {
  constexpr int KH = L2 ? HD : FD;  // valid source cols per half
  __shared__ char lds[131072];      // A @0 (64KB), B @65536 (64KB); rows 512B
  __shared__ float sred[16];
  const int tid = threadIdx.x;
  float a1 = 1.f, c1 = 0.f;
  if (L2) {
    const float m = stats_in[0] * (1.f / ((float)NN * (float)HD));
    const float var = stats_in[1] * (1.f / ((float)NN * (float)HD)) - m * m;
    const float inv = rsqrtf(var + EPSF);
    const float g = gp[0], bb = bp[0];
    a1 = g * inv; c1 = bb - g * m * inv;
  }
  const int sr = tid >> 2, q = tid & 3;
  const size_t rg = (size_t)blockIdx.x * 128 + sr;
  // ---- stage A ----
  {
    const bool half2 = (q >= 2);
    const int cbase = (q & 1) * 64;
    const float* src = (half2 ? P2 : P1) + rg * KH;
    const float sc = half2 ? ((rg < NN) ? rcv[rg] : 0.f) : 1.f;
    float v[64];
#pragma unroll
    for (int i4 = 0; i4 < 16; ++i4) {
      const int c = cbase + i4 * 4;
      float4 t = make_float4(0.f, 0.f, 0.f, 0.f);
      if (rg < NN && c < KH) t = *(const float4*)(src + c);
      float e0 = t.x, e1 = t.y, e2 = t.z, e3 = t.w;
      if (half2) { e0 *= sc; e1 *= sc; e2 *= sc; e3 *= sc; }
      else if (L2) {
        e0 = fmaxf(fmaf(a1, e0, c1), 0.f); e1 = fmaxf(fmaf(a1, e1, c1), 0.f);
        e2 = fmaxf(fmaf(a1, e2, c1), 0.f); e3 = fmaxf(fmaf(a1, e3, c1), 0.f);
      }
      v[i4 * 4 + 0] = e0; v[i4 * 4 + 1] = e1; v[i4 * 4 + 2] = e2; v[i4 * 4 + 3] = e3;
    }
    char* db = lds + sr * 512;
#pragma unroll
    for (int h = 0; h < 8; ++h) {
      short8 s8;
#pragma unroll
      for (int e = 0; e < 8; ++e) s8[e] = (short)f2bf(v[h * 8 + e]);
      *(short8*)(db + ((q * 128 + h * 16) ^ ((sr & 7) << 4))) = s8;
    }
  }
  // ---- stage B ----
  {
    const bool half2 = (q >= 2);
    const int cbase = (q & 1) * 64;
    const float* src = (half2 ? WB : WA) + (size_t)sr * KH;
    float v[64];
#pragma unroll
    for (int i4 = 0; i4 < 16; ++i4) {
      const int c = cbase + i4 * 4;
      float4 t = make_float4(0.f, 0.f, 0.f, 0.f);
      if (c < KH) t = *(const float4*)(src + c);
      v[i4 * 4 + 0] = t.x; v[i4 * 4 + 1] = t.y; v[i4 * 4 + 2] = t.z; v[i4 * 4 + 3] = t.w;
    }
    char* db = lds + 65536 + sr * 512;
#pragma unroll
    for (int h = 0; h < 8; ++h) {
      short8 s8;
#pragma unroll
      for (int e = 0; e < 8; ++e) s8[e] = (short)f2bf(v[h * 8 + e]);
      *(short8*)(db + ((q * 128 + h * 16) ^ ((sr & 7) << 4))) = s8;
    }
  }
  __syncthreads();
  // ---- compute ----
  const int w = tid >> 6, l = tid & 63, lr = l & 15, lh = l >> 4;
  short8 af[8];
  const int arow = w * 16 + lr;
#pragma unroll
  for (int kk = 0; kk < 8; ++kk)
    af[kk] = *(short8*)(lds + arow * 512 + ((lh * 16 + kk * 64) ^ ((arow & 7) << 4)));
  float ls = 0.f, lsq = 0.f;
  const char* B = lds + 65536;
#pragma unroll
  for (int nt = 0; nt < 8; ++nt) {
    f32x4 acc = {0.f, 0.f, 0.f, 0.f};
#pragma unroll
    for (int kk = 0; kk < 8; ++kk) {
      const int n = nt * 16 + lr;
      short8 bfg = *(const short8*)(B + n * 512 + ((lh * 16 + kk * 64) ^ ((n & 7) << 4)));
      acc = __builtin_amdgcn_mfma_f32_16x16x32_bf16(af[kk], bfg, acc, 0, 0, 0);
    }
    const int col = nt * 16 + lr;
#pragma unroll
    for (int r = 0; r < 4; ++r) {
      const float val = acc[r];
      const size_t rg2 = (size_t)blockIdx.x * 128 + w * 16 + lh * 4 + r;
      if (rg2 < NN) out[rg2 * HD + col] = val;
      ls += val;
      lsq = fmaf(val, val, lsq);
    }
  }
#pragma unroll
  for (int off = 32; off > 0; off >>= 1) { ls += __shfl_down(ls, off); lsq += __shfl_down(lsq, off); }
  if ((tid & 63) == 0) { sred[(tid >> 6) * 2] = ls; sred[(tid >> 6) * 2 + 1] = lsq; }
  __syncthreads();
  if (tid == 0) {
    float S = 0.f, Q = 0.f;
#pragma unroll
    for (int i = 0; i < 8; ++i) { S += sred[i * 2]; Q += sred[i * 2 + 1]; }
    atomicAdd(&so[0], S);
    atomicAdd(&so[1], Q);
  }
}

// ---------------- classifier: out = bnrelu(h2) @ Wc^T + bc ----------------
__global__ __launch_bounds__(512) void k_cls(
    const float* __restrict__ h2, const float* __restrict__ Wc,
    const float* __restrict__ bc, const float* __restrict__ stats,
    const float* __restrict__ gp, const float* __restrict__ bp,
    float* __restrict__ out) {
  __shared__ char lds[45056];  // A @0 (32KB, 256B rows), B @32768 (48 x 256B)
  const int tid = threadIdx.x;
  const float m = stats[0] * (1.f / ((float)NN * (float)HD));
  const float var = stats[1] * (1.f / ((float)NN * (float)HD)) - m * m;
  const float inv = rsqrtf(var + EPSF);
  const float g = gp[0], bb = bp[0];
  const float a2 = g * inv, c2 = bb - g * m * inv;
  const int sr = tid >> 2, q = tid & 3;
  const size_t rg = (size_t)blockIdx.x * 128 + sr;
  {
    float4 gv[8];
#pragma unroll
    for (int i4 = 0; i4 < 8; ++i4) {
      const int c = q * 32 + i4 * 4;
      float4 t = (rg < NN) ? *(const float4*)(h2 + rg * HD + c) : make_float4(0.f, 0.f, 0.f, 0.f);
      t.x = fmaxf(fmaf(a2, t.x, c2), 0.f); t.y = fmaxf(fmaf(a2, t.y, c2), 0.f);
      t.z = fmaxf(fmaf(a2, t.z, c2), 0.f); t.w = fmaxf(fmaf(a2, t.w, c2), 0.f);
      gv[i4] = t;
    }
    cvt_write256(gv, lds + sr * 256, q, sr);
  }
  if (tid < 192) {
    const int bn = tid >> 2, bq = tid & 3;
    float4 gv[8];
#pragma unroll
    for (int i4 = 0; i4 < 8; ++i4) {
      const int c = bq * 32 + i4 * 4;
      gv[i4] = (bn < CD) ? *(const float4*)(Wc + (size_t)bn * HD + c) : make_float4(0.f, 0.f, 0.f, 0.f);
    }
    cvt_write256(gv, lds + 32768 + bn * 256, bq, bn);
  }
  __syncthreads();
  const int w = tid >> 6, l = tid & 63, lr = l & 15, lh = l >> 4;
  short8 af[4];
  const int arow = w * 16 + lr;
#pragma unroll
  for (int kk = 0; kk < 4; ++kk)
    af[kk] = *(short8*)(lds + arow * 256 + ((lh * 16 + kk * 64) ^ ((arow & 7) << 4)));
#pragma unroll
  for (int nt = 0; nt < 3; ++nt) {
    f32x4 acc = {0.f, 0.f, 0.f, 0.f};
#pragma unroll
    for (int kk = 0; kk < 4; ++kk) {
      const int n = nt * 16 + lr;
      short8 bfg = *(const short8*)(lds + 32768 + n * 256 + ((lh * 16 + kk * 64) ^ ((n & 7) << 4)));
      acc = __builtin_amdgcn_mfma_f32_16x16x32_bf16(af[kk], bfg, acc, 0, 0, 0);
    }
    const int col = nt * 16 + lr;
    if (col < CD) {
      const float bias = bc[col];
#pragma unroll
      for (int r = 0; r < 4; ++r) {
        const size_t rg2 = (size_t)blockIdx.x * 128 + w * 16 + lh * 4 + r;
        if (rg2 < NN) out[rg2 * CD + col] = acc[r] + bias;
      }
    }
  }
}

extern "C" void kernel_launch(void* const* d_in, const int* in_sizes, int n_in,
                              void* d_out, int out_size, void* d_ws, size_t ws_size,
                              hipStream_t stream) {
  const float* x   = (const float*)d_in[0];
  const float* nbr = (const float*)d_in[1];
  const int*   seg = (const int*)d_in[2];
  const float* W1x = (const float*)d_in[3];
  const float* W1n = (const float*)d_in[4];
  const float* g1  = (const float*)d_in[5];
  const float* b1  = (const float*)d_in[6];
  const float* W2x = (const float*)d_in[7];
  const float* W2n = (const float*)d_in[8];
  const float* g2  = (const float*)d_in[9];
  const float* b2  = (const float*)d_in[10];
  const float* Wc  = (const float*)d_in[11];
  const float* bc  = (const float*)d_in[12];
  float* out = (float*)d_out;

  char* p = (char*)d_ws;
  auto alloc = [&](size_t bytes) {
    char* q = p;
    p += (bytes + 255) & ~(size_t)255;
    return q;
  };
  int*    rp    = (int*)   alloc(sizeof(int) * (NN + 1));
  float*  fsum  = (float*) alloc(sizeof(float) * (size_t)NN * FD);
  float*  f2sum = (float*) alloc(sizeof(float) * (size_t)NN * HD);
  float*  hpre  = (float*) alloc(sizeof(float) * (size_t)NN * HD);
  float*  h2    = (float*) alloc(sizeof(float) * (size_t)NN * HD);
  float*  stats = (float*) alloc(sizeof(float) * 4);
  unsigned short* nbr1 = (unsigned short*)alloc(sizeof(unsigned short) * (size_t)NE * HD);
  float*  es    = (float*) alloc(sizeof(float) * (size_t)NE);
  float*  eq    = (float*) alloc(sizeof(float) * (size_t)NE);
  float2* smi   = (float2*)alloc(sizeof(float2) * (size_t)NN);
  float*  rcv   = (float*) alloc(sizeof(float) * (size_t)NN);

  hipMemsetAsync(stats, 0, sizeof(float) * 4, stream);
  hipMemsetAsync(fsum, 0, sizeof(float) * (size_t)NN * FD, stream);
  hipMemsetAsync(f2sum, 0, sizeof(float) * (size_t)NN * HD, stream);

  k_rowptr<<<(NN + 256) / 256, 256, 0, stream>>>(seg, rp);
  k_gemm1<<<GRID_G1, 512, 0, stream>>>(nbr, W1x, nbr1, es, eq);
  k_f<<<NTILE, 256, 0, stream>>>(nbr, seg, fsum);
  k_nodestats<<<(NN + 255) / 256, 256, 0, stream>>>(rp, es, eq, smi, rcv);
  k_f2<<<NTILE, 256, 0, stream>>>(nbr1, seg, smi, g1, b1, f2sum);
  k_ngemm<false><<<391, 512, 0, stream>>>(x, fsum, rcv, W1x, W1n, stats, g1, b1, hpre, stats);
  k_ngemm<true><<<391, 512, 0, stream>>>(hpre, f2sum, rcv, W2x, W2n, stats, g1, b1, h2, stats + 2);
  k_cls<<<391, 512, 0, stream>>>(h2, Wc, bc, stats + 2, g2, b2, out);
}

// Round 4
// 645.978 us; speedup vs baseline: 4.0200x; 1.0000x over previous
//
#include <hip/hip_runtime.h>
#include <hip/hip_bf16.h>
#include <math.h>

#define NN 50000
#define NE 800000
#define FD 100
#define HD 128
#define CD 40
#define EPSF 1e-5f
#define NTILE 6250   // NE / 128 exactly
#define TPB_G1 5
#define GRID_G1 1250 // NTILE / TPB_G1

typedef __attribute__((ext_vector_type(8))) short short8;
typedef __attribute__((ext_vector_type(4))) float f32x4;

__device__ __forceinline__ unsigned short f2bf(float x) {
  union { __hip_bfloat16 h; unsigned short u; } cv;
  cv.h = __float2bfloat16(x);
  return cv.u;
}
__device__ __forceinline__ float bf2f(unsigned short b) {
  return __uint_as_float(((unsigned)b) << 16);
}

// row_ptr[i] = first edge index with seg_ids >= i
__global__ void k_rowptr(const int* __restrict__ seg, int* __restrict__ rp) {
  int i = blockIdx.x * blockDim.x + threadIdx.x;
  if (i > NN) return;
  int lo = 0, hi = NE;
  while (lo < hi) { int mid = (lo + hi) >> 1; if (seg[mid] < i) lo = mid + 1; else hi = mid; }
  rp[i] = lo;
}

// convert 32 f32 (in 8 float4) -> 4 swizzled short8 LDS writes (row stride 256B)
__device__ __forceinline__ void cvt_write256(const float4* gv, char* rowbase, int q, int sr) {
  const float* vf = (const float*)gv;
#pragma unroll
  for (int h = 0; h < 4; ++h) {
    short8 s;
#pragma unroll
    for (int e = 0; e < 8; ++e) s[e] = (short)f2bf(vf[h * 8 + e]);
    *(short8*)(rowbase + ((q * 64 + h * 16) ^ ((sr & 7) << 4))) = s;
  }
}

// ---------------- edge GEMM: nbr1 = bf16(nbr @ W1x^T), es/eq row stats ----------------
__global__ __launch_bounds__(512, 2) void k_gemm1(
    const float* __restrict__ nbr, const float* __restrict__ W1x,
    unsigned short* __restrict__ nbr1,
    float* __restrict__ es, float* __restrict__ eq) {
  __shared__ char lds[65536];  // two 32KB A buffers; buf0 doubles as B staging at start
  const int tid = threadIdx.x;
  const int sr = tid >> 2, q = tid & 3;
  const int w = tid >> 6, l = tid & 63, lr = l & 15, lh = l >> 4;

  // stage B = W1x (128 x 100 f32) -> bf16 swizzled into buf0
  {
    float4 gv[8];
    const float* src = W1x + (size_t)sr * FD;
#pragma unroll
    for (int i4 = 0; i4 < 8; ++i4) {
      const int c = q * 32 + i4 * 4;
      gv[i4] = (c < FD) ? *(const float4*)(src + c) : make_float4(0.f, 0.f, 0.f, 0.f);
    }
    cvt_write256(gv, lds + sr * 256, q, sr);
  }
  __syncthreads();
  // B fragments -> registers (reused for all tiles)
  short8 bfr[8][4];
#pragma unroll
  for (int nt = 0; nt < 8; ++nt) {
#pragma unroll
    for (int kk = 0; kk < 4; ++kk) {
      const int n = nt * 16 + lr;
      bfr[nt][kk] = *(short8*)(lds + n * 256 + ((lh * 16 + kk * 64) ^ ((n & 7) << 4)));
    }
  }
  __syncthreads();

  const int t0 = blockIdx.x * TPB_G1;
  float4 gv[8];
  // prologue: stage tile t0 into buf0
  {
    const float* src = nbr + (size_t)(t0 * 128 + sr) * FD;
#pragma unroll
    for (int i4 = 0; i4 < 8; ++i4) {
      const int c = q * 32 + i4 * 4;
      gv[i4] = (c < FD) ? *(const float4*)(src + c) : make_float4(0.f, 0.f, 0.f, 0.f);
    }
    cvt_write256(gv, lds + sr * 256, q, sr);
  }
  int cur = 0;
  for (int s = 0; s < TPB_G1; ++s) {
    // issue next tile's global loads early (latency hides under MFMA)
    if (s + 1 < TPB_G1) {
      const float* src = nbr + (size_t)((t0 + s + 1) * 128 + sr) * FD;
#pragma unroll
      for (int i4 = 0; i4 < 8; ++i4) {
        const int c = q * 32 + i4 * 4;
        gv[i4] = (c < FD) ? *(const float4*)(src + c) : make_float4(0.f, 0.f, 0.f, 0.f);
      }
    }
    __syncthreads();  // buf[cur] ready
    char* bufc = lds + cur * 32768;
    short8 af[4];
    const int arow = w * 16 + lr;
#pragma unroll
    for (int kk = 0; kk < 4; ++kk)
      af[kk] = *(short8*)(bufc + arow * 256 + ((lh * 16 + kk * 64) ^ ((arow & 7) << 4)));

    const size_t rowb = (size_t)(t0 + s) * 128;
    float rs[4] = {0.f, 0.f, 0.f, 0.f}, rq[4] = {0.f, 0.f, 0.f, 0.f};
#pragma unroll
    for (int nt = 0; nt < 8; ++nt) {
      f32x4 acc = {0.f, 0.f, 0.f, 0.f};
#pragma unroll
      for (int kk = 0; kk < 4; ++kk)
        acc = __builtin_amdgcn_mfma_f32_16x16x32_bf16(af[kk], bfr[nt][kk], acc, 0, 0, 0);
      const int col = nt * 16 + lr;
#pragma unroll
      for (int r = 0; r < 4; ++r) {
        const float val = acc[r];
        nbr1[(rowb + w * 16 + lh * 4 + r) * HD + col] = f2bf(val);
        rs[r] += val;
        rq[r] = fmaf(val, val, rq[r]);
      }
    }
#pragma unroll
    for (int r = 0; r < 4; ++r) {
      float a = rs[r], b = rq[r];
#pragma unroll
      for (int off = 1; off < 16; off <<= 1) { a += __shfl_xor(a, off); b += __shfl_xor(b, off); }
      if (lr == 0) {
        const size_t rg = rowb + w * 16 + lh * 4 + r;
        es[rg] = a; eq[rg] = b;
      }
    }
    if (s + 1 < TPB_G1) cvt_write256(gv, lds + (cur ^ 1) * 32768 + sr * 256, q, sr);
    cur ^= 1;
  }
}

// ---------------- segment sums, coalesced chunk + boundary atomics ----------------
__global__ __launch_bounds__(256) void k_f(
    const float* __restrict__ nbr, const int* __restrict__ seg, float* __restrict__ fsum) {
  __shared__ float L[128][104];
  __shared__ int segL[128];
  const int tid = threadIdx.x;
  const size_t base = (size_t)blockIdx.x * 128;
  for (int idx = tid; idx < 3200; idx += 256) {
    const int row = idx / 25, c4 = idx - row * 25;
    float4 v = *(const float4*)(nbr + (base + row) * FD + c4 * 4);
    *(float4*)&L[row][c4 * 4] = v;
  }
  if (tid < 128) segL[tid] = seg[base + tid];
  __syncthreads();
  if (tid < FD) {
    const int nd0 = segL[0], ndL = segL[127];
    int curn = nd0; float acc = 0.f;
    for (int row = 0; row < 128; ++row) {
      const int nd = segL[row];
      if (nd != curn) {
        if (curn == nd0 || curn == ndL) atomicAdd(&fsum[(size_t)curn * FD + tid], acc);
        else fsum[(size_t)curn * FD + tid] = acc;
        acc = 0.f; curn = nd;
      }
      acc += L[row][tid];
    }
    atomicAdd(&fsum[(size_t)curn * FD + tid], acc);
  }
}

__global__ void k_nodestats(const int* __restrict__ rp, const float* __restrict__ es,
                            const float* __restrict__ eq, float2* __restrict__ smi,
                            float* __restrict__ rcv) {
  const int i = blockIdx.x * blockDim.x + threadIdx.x;
  if (i >= NN) return;
  const int s = rp[i], e = rp[i + 1];
  float S = 0.f, Q = 0.f;
  for (int ed = s; ed < e; ++ed) { S += es[ed]; Q += eq[ed]; }
  const int cnt = e - s;
  const float ne = fmaxf((float)cnt * (float)HD, 1.f);
  const float sm = S / ne;
  const float var = Q / ne - sm * sm;
  smi[i] = make_float2(sm, rsqrtf(var + EPSF));
  rcv[i] = 1.f / (float)(cnt > 0 ? cnt : 1);
}

__global__ __launch_bounds__(256) void k_f2(
    const unsigned short* __restrict__ nbr1, const int* __restrict__ seg,
    const float2* __restrict__ smi, const float* __restrict__ g1p,
    const float* __restrict__ b1p, float* __restrict__ f2sum) {
  __shared__ float L[128][132];
  __shared__ int segL[128];
  __shared__ float2 smrow[128];
  const int tid = threadIdx.x;
  const size_t base = (size_t)blockIdx.x * 128;
  for (int idx = tid; idx < 2048; idx += 256) {
    const int row = idx >> 4, c8 = idx & 15;
    short8 v = *(const short8*)(nbr1 + (base + row) * HD + c8 * 8);
    float4 a, b;
    a.x = bf2f((unsigned short)v[0]); a.y = bf2f((unsigned short)v[1]);
    a.z = bf2f((unsigned short)v[2]); a.w = bf2f((unsigned short)v[3]);
    b.x = bf2f((unsigned short)v[4]); b.y = bf2f((unsigned short)v[5]);
    b.z = bf2f((unsigned short)v[6]); b.w = bf2f((unsigned short)v[7]);
    *(float4*)&L[row][c8 * 8] = a;
    *(float4*)&L[row][c8 * 8 + 4] = b;
  }
  if (tid < 128) {
    const int nd = seg[base + tid];
    segL[tid] = nd;
    smrow[tid] = smi[nd];
  }
  __syncthreads();
  const float g = g1p[0], bb = b1p[0];
  if (tid < HD) {
    const int nd0 = segL[0], ndL = segL[127];
    int curn = nd0; float acc = 0.f;
    for (int row = 0; row < 128; ++row) {
      const int nd = segL[row];
      if (nd != curn) {
        if (curn == nd0 || curn == ndL) atomicAdd(&f2sum[(size_t)curn * HD + tid], acc);
        else f2sum[(size_t)curn * HD + tid] = acc;
        acc = 0.f; curn = nd;
      }
      const float2 mi = smrow[row];
      acc += fmaxf(fmaf(g, (L[row][tid] - mi.x) * mi.y, bb), 0.f);
    }
    atomicAdd(&f2sum[(size_t)curn * HD + tid], acc);
  }
}

// ---------------- node GEMMs (MFMA, K=256 two-half) ----------------
// L2=false: out = x@W1x^T + (fsum*rcv)@W1n^T, stats -> so[0..1]
// L2=true : out = bnrelu(hpre)@W2x^T + (f2sum*rcv)@W2n^T, stats -> so[0..1]
template <bool L2>
__global__ __launch_bounds__(512) void k_ngemm(
    const float* __restrict__ P1, const float* __restrict__ P2,
    const float* __restrict__ rcv,
    const float* __restrict__ WA, const float* __restrict__ WB,
    const float* __restrict__ stats_in,
    const float* __restrict__ gp, const float* __restrict__ bp,
    float* __restrict__ out, float* __restrict__ so) {
  constexpr int KH = L2 ? HD : FD;  // valid source cols per half
  __shared__ char lds[131072];      // A @0 (64KB), B @65536 (64KB); rows 512B
  __shared__ float sred[16];
  const int tid = threadIdx.x;
  float a1 = 1.f, c1 = 0.f;
  if (L2) {
    const float m = stats_in[0] * (1.f / ((float)NN * (float)HD));
    const float var = stats_in[1] * (1.f / ((float)NN * (float)HD)) - m * m;
    const float inv = rsqrtf(var + EPSF);
    const float g = gp[0], bb = bp[0];
    a1 = g * inv; c1 = bb - g * m * inv;
  }
  const int sr = tid >> 2, q = tid & 3;
  const size_t rg = (size_t)blockIdx.x * 128 + sr;
  // ---- stage A ----
  {
    const bool half2 = (q >= 2);
    const int cbase = (q & 1) * 64;
    const float* src = (half2 ? P2 : P1) + rg * KH;
    const float sc = half2 ? ((rg < NN) ? rcv[rg] : 0.f) : 1.f;
    float v[64];
#pragma unroll
    for (int i4 = 0; i4 < 16; ++i4) {
      const int c = cbase + i4 * 4;
      float4 t = make_float4(0.f, 0.f, 0.f, 0.f);
      if (rg < NN && c < KH) t = *(const float4*)(src + c);
      float e0 = t.x, e1 = t.y, e2 = t.z, e3 = t.w;
      if (half2) { e0 *= sc; e1 *= sc; e2 *= sc; e3 *= sc; }
      else if (L2) {
        e0 = fmaxf(fmaf(a1, e0, c1), 0.f); e1 = fmaxf(fmaf(a1, e1, c1), 0.f);
        e2 = fmaxf(fmaf(a1, e2, c1), 0.f); e3 = fmaxf(fmaf(a1, e3, c1), 0.f);
      }
      v[i4 * 4 + 0] = e0; v[i4 * 4 + 1] = e1; v[i4 * 4 + 2] = e2; v[i4 * 4 + 3] = e3;
    }
    char* db = lds + sr * 512;
#pragma unroll
    for (int h = 0; h < 8; ++h) {
      short8 s8;
#pragma unroll
      for (int e = 0; e < 8; ++e) s8[e] = (short)f2bf(v[h * 8 + e]);
      *(short8*)(db + ((q * 128 + h * 16) ^ ((sr & 7) << 4))) = s8;
    }
  }
  // ---- stage B ----
  {
    const bool half2 = (q >= 2);
    const int cbase = (q & 1) * 64;
    const float* src = (half2 ? WB : WA) + (size_t)sr * KH;
    float v[64];
#pragma unroll
    for (int i4 = 0; i4 < 16; ++i4) {
      const int c = cbase + i4 * 4;
      float4 t = make_float4(0.f, 0.f, 0.f, 0.f);
      if (c < KH) t = *(const float4*)(src + c);
      v[i4 * 4 + 0] = t.x; v[i4 * 4 + 1] = t.y; v[i4 * 4 + 2] = t.z; v[i4 * 4 + 3] = t.w;
    }
    char* db = lds + 65536 + sr * 512;
#pragma unroll
    for (int h = 0; h < 8; ++h) {
      short8 s8;
#pragma unroll
      for (int e = 0; e < 8; ++e) s8[e] = (short)f2bf(v[h * 8 + e]);
      *(short8*)(db + ((q * 128 + h * 16) ^ ((sr & 7) << 4))) = s8;
    }
  }
  __syncthreads();
  // ---- compute ----
  const int w = tid >> 6, l = tid & 63, lr = l & 15, lh = l >> 4;
  short8 af[8];
  const int arow = w * 16 + lr;
#pragma unroll
  for (int kk = 0; kk < 8; ++kk)
    af[kk] = *(short8*)(lds + arow * 512 + ((lh * 16 + kk * 64) ^ ((arow & 7) << 4)));
  float ls = 0.f, lsq = 0.f;
  const char* B = lds + 65536;
#pragma unroll
  for (int nt = 0; nt < 8; ++nt) {
    f32x4 acc = {0.f, 0.f, 0.f, 0.f};
#pragma unroll
    for (int kk = 0; kk < 8; ++kk) {
      const int n = nt * 16 + lr;
      short8 bfg = *(const short8*)(B + n * 512 + ((lh * 16 + kk * 64) ^ ((n & 7) << 4)));
      acc = __builtin_amdgcn_mfma_f32_16x16x32_bf16(af[kk], bfg, acc, 0, 0, 0);
    }
    const int col = nt * 16 + lr;
#pragma unroll
    for (int r = 0; r < 4; ++r) {
      const float val = acc[r];
      const size_t rg2 = (size_t)blockIdx.x * 128 + w * 16 + lh * 4 + r;
      if (rg2 < NN) out[rg2 * HD + col] = val;
      ls += val;
      lsq = fmaf(val, val, lsq);
    }
  }
#pragma unroll
  for (int off = 32; off > 0; off >>= 1) { ls += __shfl_down(ls, off); lsq += __shfl_down(lsq, off); }
  if ((tid & 63) == 0) { sred[(tid >> 6) * 2] = ls; sred[(tid >> 6) * 2 + 1] = lsq; }
  __syncthreads();
  if (tid == 0) {
    float S = 0.f, Q = 0.f;
#pragma unroll
    for (int i = 0; i < 8; ++i) { S += sred[i * 2]; Q += sred[i * 2 + 1]; }
    atomicAdd(&so[0], S);
    atomicAdd(&so[1], Q);
  }
}

// ---------------- classifier: out = bnrelu(h2) @ Wc^T + bc ----------------
__global__ __launch_bounds__(512) void k_cls(
    const float* __restrict__ h2, const float* __restrict__ Wc,
    const float* __restrict__ bc, const float* __restrict__ stats,
    const float* __restrict__ gp, const float* __restrict__ bp,
    float* __restrict__ out) {
  __shared__ char lds[45056];  // A @0 (32KB, 256B rows), B @32768 (48 x 256B)
  const int tid = threadIdx.x;
  const float m = stats[0] * (1.f / ((float)NN * (float)HD));
  const float var = stats[1] * (1.f / ((float)NN * (float)HD)) - m * m;
  const float inv = rsqrtf(var + EPSF);
  const float g = gp[0], bb = bp[0];
  const float a2 = g * inv, c2 = bb - g * m * inv;
  const int sr = tid >> 2, q = tid & 3;
  const size_t rg = (size_t)blockIdx.x * 128 + sr;
  {
    float4 gv[8];
#pragma unroll
    for (int i4 = 0; i4 < 8; ++i4) {
      const int c = q * 32 + i4 * 4;
      float4 t = (rg < NN) ? *(const float4*)(h2 + rg * HD + c) : make_float4(0.f, 0.f, 0.f, 0.f);
      t.x = fmaxf(fmaf(a2, t.x, c2), 0.f); t.y = fmaxf(fmaf(a2, t.y, c2), 0.f);
      t.z = fmaxf(fmaf(a2, t.z, c2), 0.f); t.w = fmaxf(fmaf(a2, t.w, c2), 0.f);
      gv[i4] = t;
    }
    cvt_write256(gv, lds + sr * 256, q, sr);
  }
  if (tid < 192) {
    const int bn = tid >> 2, bq = tid & 3;
    float4 gv[8];
#pragma unroll
    for (int i4 = 0; i4 < 8; ++i4) {
      const int c = bq * 32 + i4 * 4;
      gv[i4] = (bn < CD) ? *(const float4*)(Wc + (size_t)bn * HD + c) : make_float4(0.f, 0.f, 0.f, 0.f);
    }
    cvt_write256(gv, lds + 32768 + bn * 256, bq, bn);
  }
  __syncthreads();
  const int w = tid >> 6, l = tid & 63, lr = l & 15, lh = l >> 4;
  short8 af[4];
  const int arow = w * 16 + lr;
#pragma unroll
  for (int kk = 0; kk < 4; ++kk)
    af[kk] = *(short8*)(lds + arow * 256 + ((lh * 16 + kk * 64) ^ ((arow & 7) << 4)));
#pragma unroll
  for (int nt = 0; nt < 3; ++nt) {
    f32x4 acc = {0.f, 0.f, 0.f, 0.f};
#pragma unroll
    for (int kk = 0; kk < 4; ++kk) {
      const int n = nt * 16 + lr;
      short8 bfg = *(const short8*)(lds + 32768 + n * 256 + ((lh * 16 + kk * 64) ^ ((n & 7) << 4)));
      acc = __builtin_amdgcn_mfma_f32_16x16x32_bf16(af[kk], bfg, acc, 0, 0, 0);
    }
    const int col = nt * 16 + lr;
    if (col < CD) {
      const float bias = bc[col];
#pragma unroll
      for (int r = 0; r < 4; ++r) {
        const size_t rg2 = (size_t)blockIdx.x * 128 + w * 16 + lh * 4 + r;
        if (rg2 < NN) out[rg2 * CD + col] = acc[r] + bias;
      }
    }
  }
}

extern "C" void kernel_launch(void* const* d_in, const int* in_sizes, int n_in,
                              void* d_out, int out_size, void* d_ws, size_t ws_size,
                              hipStream_t stream) {
  const float* x   = (const float*)d_in[0];
  const float* nbr = (const float*)d_in[1];
  const int*   seg = (const int*)d_in[2];
  const float* W1x = (const float*)d_in[3];
  const float* W1n = (const float*)d_in[4];
  const float* g1  = (const float*)d_in[5];
  const float* b1  = (const float*)d_in[6];
  const float* W2x = (const float*)d_in[7];
  const float* W2n = (const float*)d_in[8];
  const float* g2  = (const float*)d_in[9];
  const float* b2  = (const float*)d_in[10];
  const float* Wc  = (const float*)d_in[11];
  const float* bc  = (const float*)d_in[12];
  float* out = (float*)d_out;

  char* p = (char*)d_ws;
  auto alloc = [&](size_t bytes) {
    char* q = p;
    p += (bytes + 255) & ~(size_t)255;
    return q;
  };
  int*    rp    = (int*)   alloc(sizeof(int) * (NN + 1));
  float*  fsum  = (float*) alloc(sizeof(float) * (size_t)NN * FD);
  float*  f2sum = (float*) alloc(sizeof(float) * (size_t)NN * HD);
  float*  hpre  = (float*) alloc(sizeof(float) * (size_t)NN * HD);
  float*  h2    = (float*) alloc(sizeof(float) * (size_t)NN * HD);
  float*  stats = (float*) alloc(sizeof(float) * 4);
  unsigned short* nbr1 = (unsigned short*)alloc(sizeof(unsigned short) * (size_t)NE * HD);
  float*  es    = (float*) alloc(sizeof(float) * (size_t)NE);
  float*  eq    = (float*) alloc(sizeof(float) * (size_t)NE);
  float2* smi   = (float2*)alloc(sizeof(float2) * (size_t)NN);
  float*  rcv   = (float*) alloc(sizeof(float) * (size_t)NN);

  hipMemsetAsync(stats, 0, sizeof(float) * 4, stream);
  hipMemsetAsync(fsum, 0, sizeof(float) * (size_t)NN * FD, stream);
  hipMemsetAsync(f2sum, 0, sizeof(float) * (size_t)NN * HD, stream);

  k_rowptr<<<(NN + 256) / 256, 256, 0, stream>>>(seg, rp);
  k_gemm1<<<GRID_G1, 512, 0, stream>>>(nbr, W1x, nbr1, es, eq);
  k_f<<<NTILE, 256, 0, stream>>>(nbr, seg, fsum);
  k_nodestats<<<(NN + 255) / 256, 256, 0, stream>>>(rp, es, eq, smi, rcv);
  k_f2<<<NTILE, 256, 0, stream>>>(nbr1, seg, smi, g1, b1, f2sum);
  k_ngemm<false><<<391, 512, 0, stream>>>(x, fsum, rcv, W1x, W1n, stats, g1, b1, hpre, stats);
  k_ngemm<true><<<391, 512, 0, stream>>>(hpre, f2sum, rcv, W2x, W2n, stats, g1, b1, h2, stats + 2);
  k_cls<<<391, 512, 0, stream>>>(h2, Wc, bc, stats + 2, g2, b2, out);
}